// Round 3
// baseline (2199.948 us; speedup 1.0000x reference)
//
#include <hip/hip_runtime.h>
#include <cmath>

// ---------------------------------------------------------------------------
// MoEProjector: router(softmax,top2) -> per-expert [Linear -> GELU -> Linear]
// -> gate-weighted combine -> *gate_scale -> LayerNorm.
// T=8192 tokens, D=1024, O=4096, E=4, top-2.
// R3: BK=64 K-loop + XOR-8 LDS swizzle (kills bank conflicts, halves barrier
// drains), atomic-add combine epilogue (kills RMW read latency),
// vectorized transpose stores.
// ---------------------------------------------------------------------------

typedef float f32x4 __attribute__((ext_vector_type(4)));
typedef __bf16 bf16x8 __attribute__((ext_vector_type(8)));
typedef __bf16 bf16x4 __attribute__((ext_vector_type(4)));

#define T_TOK 8192
#define DDIM 1024
#define ODIM 4096
#define NEXP 4

__device__ __forceinline__ void gl_lds16(const void* g, void* l) {
    __builtin_amdgcn_global_load_lds(
        (const __attribute__((address_space(1))) void*)g,
        (__attribute__((address_space(3))) void*)l, 16, 0, 0);
}

// ---------------- x fp32 -> bf16 (vectorized) ----------------
__global__ __launch_bounds__(256) void cvt_bf16_vec(const float* __restrict__ in,
                                                    __bf16* __restrict__ out, int n4) {
    int i = blockIdx.x * 256 + threadIdx.x;
    if (i >= n4) return;
    float4 v = ((const float4*)in)[i];
    bf16x4 o = { (__bf16)v.x, (__bf16)v.y, (__bf16)v.z, (__bf16)v.w };
    ((bf16x4*)out)[i] = o;
}

// ------------- W [R,C] fp32 -> Wt [C,R] bf16, per expert (z) -------------
// 64x64 tile; fp32 LDS pad-65 (2-way banks both phases); 8B bf16x4 stores.
__global__ __launch_bounds__(256) void transpose_cvt(const float* __restrict__ in,
                                                     __bf16* __restrict__ out,
                                                     int R, int C) {
    __shared__ float tile[64][65];
    const size_t eoff = (size_t)blockIdx.z * R * C;
    const float* ip = in + eoff;
    __bf16* op = out + eoff;
    const int c0 = blockIdx.x * 64, r0 = blockIdx.y * 64;
    const int tid = threadIdx.x;
    const int rr = tid >> 4, c4 = (tid & 15) * 4;
#pragma unroll
    for (int i = 0; i < 4; i++) {
        const int r = rr + i * 16;
        float4 v = *(const float4*)(ip + (size_t)(r0 + r) * C + c0 + c4);
        tile[r][c4 + 0] = v.x; tile[r][c4 + 1] = v.y;
        tile[r][c4 + 2] = v.z; tile[r][c4 + 3] = v.w;
    }
    __syncthreads();
    const int cc = tid >> 4, r4 = (tid & 15) * 4;
#pragma unroll
    for (int i = 0; i < 4; i++) {
        const int c = cc + i * 16;
        bf16x4 o = { (__bf16)tile[r4 + 0][c], (__bf16)tile[r4 + 1][c],
                     (__bf16)tile[r4 + 2][c], (__bf16)tile[r4 + 3][c] };
        *(bf16x4*)(op + (size_t)(c0 + c) * R + r0 + r4) = o;
    }
}

// -------- router: fp32 logits -> softmax -> top2 -> compacted lists --------
__global__ __launch_bounds__(256) void router_kernel(const float* __restrict__ x,
                                                     const float* __restrict__ Wg,
                                                     const float* __restrict__ bg,
                                                     int* __restrict__ counts,
                                                     int* __restrict__ perm,
                                                     float* __restrict__ wlist) {
    const int wave = threadIdx.x >> 6, lane = threadIdx.x & 63;
    const int t = blockIdx.x * 4 + wave;
    const float* xr = x + (size_t)t * DDIM;
    float a0 = 0.f, a1 = 0.f, a2 = 0.f, a3 = 0.f;
    const float4* Wg4 = (const float4*)Wg;  // Wg[d*4 + e] contiguous over e
    for (int d = lane; d < DDIM; d += 64) {
        float xv = xr[d];
        float4 w = Wg4[d];
        a0 += xv * w.x; a1 += xv * w.y; a2 += xv * w.z; a3 += xv * w.w;
    }
#pragma unroll
    for (int off = 32; off; off >>= 1) {
        a0 += __shfl_xor(a0, off); a1 += __shfl_xor(a1, off);
        a2 += __shfl_xor(a2, off); a3 += __shfl_xor(a3, off);
    }
    if (lane == 0) {
        float l[4] = {a0 + bg[0], a1 + bg[1], a2 + bg[2], a3 + bg[3]};
        float mx = fmaxf(fmaxf(l[0], l[1]), fmaxf(l[2], l[3]));
        float p[4], s = 0.f;
#pragma unroll
        for (int e = 0; e < 4; e++) { p[e] = expf(l[e] - mx); s += p[e]; }
#pragma unroll
        for (int e = 0; e < 4; e++) p[e] /= s;
        int e1 = 0;  // argmax, lowest index on ties (strict >)
#pragma unroll
        for (int e = 1; e < 4; e++) if (p[e] > p[e1]) e1 = e;
        int e2 = (e1 == 0) ? 1 : 0;
#pragma unroll
        for (int e = 0; e < 4; e++) if (e != e1 && p[e] > p[e2]) e2 = e;
        const float inv = 1.0f / (p[e1] + p[e2]);
        int pos1 = atomicAdd(&counts[e1], 1);
        perm[e1 * T_TOK + pos1] = t;
        wlist[e1 * T_TOK + pos1] = p[e1] * inv;
        int pos2 = atomicAdd(&counts[e2], 1);
        perm[e2 * T_TOK + pos2] = t;
        wlist[e2 * T_TOK + pos2] = p[e2] * inv;
    }
}

// ------- GEMM C[M,N] = A[M,K] @ B^T[N,K]  (bf16 in, fp32 acc), gathered -----
// BK=64, 128x128 tile. LDS chunk swizzle: slot (row, c) holds global chunk
// (row, c ^ (row&7)) -> fragment ds_read_b128s spread over all 8 bank groups
// while global_load_lds staging stays linear (wave base + lane*16B).
// MODE 0: A rows gathered via perm (tokens);  H[i] = gelu(acc + b1) -> bf16
// MODE 1: A = H dense rows;  atomicAdd(out[perm[i]], wlist[i]*(acc + b2))
template <int MODE, int KDIM>
__global__ __launch_bounds__(256) void moe_gemm(const __bf16* __restrict__ A,
                                                const __bf16* __restrict__ B,
                                                const float* __restrict__ bias,
                                                __bf16* __restrict__ Hout,
                                                float* __restrict__ Fout,
                                                const int* __restrict__ perm,
                                                const float* __restrict__ wlist,
                                                const int* __restrict__ countp) {
    constexpr int BK = 64;
    __shared__ __align__(16) __bf16 As[128 * BK];
    __shared__ __align__(16) __bf16 Bs[128 * BK];
    const int count = *countp;
    const int m0 = blockIdx.y * 128;
    if (m0 >= count) return;  // block-uniform early exit
    const int tid = threadIdx.x;
    const int wave = tid >> 6, lane = tid & 63;
    const int r16 = lane & 15, quad = lane >> 4;
    const int n0 = blockIdx.x * 128;
    const int wm = (wave & 1) * 64, wn = (wave >> 1) * 64;

    // Staging: 128x64 tile = 1024 16B-chunks, 4 per thread.
    // chunk c -> row c>>3, LDS slot col c&7, global data col (c&7)^(row&7).
    const __bf16 *Ag[4], *Bg[4];
    __bf16 *sA[4], *sB[4];
#pragma unroll
    for (int g = 0; g < 4; g++) {
        const int c = tid + g * 256;
        const int row = c >> 3;
        const int col = (((c & 7) ^ (row & 7))) * 8;
        if (MODE == 0)
            Ag[g] = A + (size_t)perm[m0 + row] * KDIM + col;
        else
            Ag[g] = A + (size_t)(m0 + row) * KDIM + col;
        Bg[g] = B + (size_t)(n0 + row) * KDIM + col;
        sA[g] = &As[(g * 256 + wave * 64) * 8];
        sB[g] = &Bs[(g * 256 + wave * 64) * 8];
    }

    f32x4 acc[4][4] = {};

    for (int k0 = 0; k0 < KDIM; k0 += BK) {
#pragma unroll
        for (int g = 0; g < 4; g++) gl_lds16(Ag[g] + k0, sA[g]);
#pragma unroll
        for (int g = 0; g < 4; g++) gl_lds16(Bg[g] + k0, sB[g]);
        __syncthreads();
#pragma unroll
        for (int kk = 0; kk < 2; kk++) {
            bf16x8 af[4], bfr[4];
#pragma unroll
            for (int i = 0; i < 4; i++) {
                const int row = wm + i * 16 + r16;
                const int cc = (kk * 4 + quad) ^ (row & 7);
                af[i] = *(const bf16x8*)&As[row * BK + cc * 8];
            }
#pragma unroll
            for (int i = 0; i < 4; i++) {
                const int row = wn + i * 16 + r16;
                const int cc = (kk * 4 + quad) ^ (row & 7);
                bfr[i] = *(const bf16x8*)&Bs[row * BK + cc * 8];
            }
#pragma unroll
            for (int mi = 0; mi < 4; mi++)
#pragma unroll
                for (int ni = 0; ni < 4; ni++)
                    acc[mi][ni] = __builtin_amdgcn_mfma_f32_16x16x32_bf16(
                        af[mi], bfr[ni], acc[mi][ni], 0, 0, 0);
        }
        __syncthreads();
    }

    // Epilogue. D layout: row(m) = quad*4 + reg, col(n) = lane&15.
    const int colBase = n0 + wn + r16;
    if (MODE == 0) {
#pragma unroll
        for (int mi = 0; mi < 4; mi++) {
            const int rowBase = m0 + wm + mi * 16 + quad * 4;
#pragma unroll
            for (int ni = 0; ni < 4; ni++) {
                const int col = colBase + ni * 16;
                const float bv = bias[col];
#pragma unroll
                for (int r = 0; r < 4; r++) {
                    if (rowBase + r < count) {
                        float xv = acc[mi][ni][r] + bv;
                        // tanh-form GELU: x * sigmoid(1.59577*x*(1+0.044715*x^2))
                        float u = 1.5957691216057308f * xv * (1.0f + 0.044715f * xv * xv);
                        float gv = xv * __builtin_amdgcn_rcpf(1.0f + __expf(-u));
                        Hout[(size_t)(rowBase + r) * ODIM + col] = (__bf16)gv;
                    }
                }
            }
        }
    } else {
#pragma unroll
        for (int mi = 0; mi < 4; mi++) {
            const int rowBase = m0 + wm + mi * 16 + quad * 4;
            int tok[4]; float g[4]; bool ok[4];
#pragma unroll
            for (int r = 0; r < 4; r++) {
                const int i = rowBase + r;
                ok[r] = (i < count);
                tok[r] = ok[r] ? perm[i] : 0;
                g[r] = ok[r] ? wlist[i] : 0.f;
            }
#pragma unroll
            for (int ni = 0; ni < 4; ni++) {
                const int col = colBase + ni * 16;
                const float bv = bias[col];
#pragma unroll
                for (int r = 0; r < 4; r++) {
                    if (ok[r]) {
                        // Fire-and-forget fp32 add at L2 (native atomic, no readback).
                        unsafeAtomicAdd(&Fout[(size_t)tok[r] * ODIM + col],
                                        g[r] * (acc[mi][ni][r] + bv));
                    }
                }
            }
        }
    }
}

// ---------------- in-place LayerNorm over last dim (4096) ----------------
__global__ __launch_bounds__(256) void ln_kernel(float* __restrict__ out,
                                                 const float* __restrict__ lw,
                                                 const float* __restrict__ lb,
                                                 const float* __restrict__ gsp) {
    const int t = blockIdx.x;
    float* row = out + (size_t)t * ODIM;
    const float gs = gsp[0];
    float4 v[4];
    float s = 0.f, ss = 0.f;
#pragma unroll
    for (int i = 0; i < 4; i++) {
        float4 a = ((const float4*)row)[threadIdx.x + i * 256];
        a.x *= gs; a.y *= gs; a.z *= gs; a.w *= gs;
        v[i] = a;
        s += a.x + a.y + a.z + a.w;
        ss += a.x * a.x + a.y * a.y + a.z * a.z + a.w * a.w;
    }
#pragma unroll
    for (int off = 32; off; off >>= 1) {
        s += __shfl_xor(s, off);
        ss += __shfl_xor(ss, off);
    }
    __shared__ float rs[4], rss[4];
    const int wave = threadIdx.x >> 6, lane = threadIdx.x & 63;
    if (lane == 0) { rs[wave] = s; rss[wave] = ss; }
    __syncthreads();
    s = rs[0] + rs[1] + rs[2] + rs[3];
    ss = rss[0] + rss[1] + rss[2] + rss[3];
    const float mu = s * (1.0f / ODIM);
    const float var = ss * (1.0f / ODIM) - mu * mu;
    const float inv = 1.0f / sqrtf(var + 1e-5f);
#pragma unroll
    for (int i = 0; i < 4; i++) {
        const int c4 = threadIdx.x + i * 256;
        float4 w4 = ((const float4*)lw)[c4];
        float4 b4 = ((const float4*)lb)[c4];
        float4 o;
        o.x = (v[i].x - mu) * inv * w4.x + b4.x;
        o.y = (v[i].y - mu) * inv * w4.y + b4.y;
        o.z = (v[i].z - mu) * inv * w4.z + b4.z;
        o.w = (v[i].w - mu) * inv * w4.w + b4.w;
        ((float4*)row)[c4] = o;
    }
}

extern "C" void kernel_launch(void* const* d_in, const int* in_sizes, int n_in,
                              void* d_out, int out_size, void* d_ws, size_t ws_size,
                              hipStream_t stream) {
    const float* x   = (const float*)d_in[0];
    const float* Wg  = (const float*)d_in[1];
    const float* bg  = (const float*)d_in[2];
    const float* W1  = (const float*)d_in[3];
    const float* b1  = (const float*)d_in[4];
    const float* W2  = (const float*)d_in[5];
    const float* b2  = (const float*)d_in[6];
    const float* lnw = (const float*)d_in[7];
    const float* lnb = (const float*)d_in[8];
    const float* gsc = (const float*)d_in[9];
    float* out = (float*)d_out;

    // Workspace layout (~240 MB)
    char* w = (char*)d_ws;
    __bf16* Xb  = (__bf16*)w;                          // T*D bf16      = 16 MB
    __bf16* W1T = Xb + (size_t)T_TOK * DDIM;           // E*O*D bf16    = 32 MB
    __bf16* W2T = W1T + (size_t)NEXP * ODIM * DDIM;    // E*O*O bf16    = 128 MB
    __bf16* H   = W2T + (size_t)NEXP * ODIM * ODIM;    // T*O bf16      = 64 MB (per-expert reuse)
    int*   counts = (int*)(H + (size_t)T_TOK * ODIM);  // E ints
    int*   perm   = counts + NEXP;                     // E*T ints
    float* wlist  = (float*)(perm + NEXP * T_TOK);     // E*T floats

    // Zero routing lists (perm padding -> token 0) and the output accumulator.
    hipMemsetAsync(counts, 0, (NEXP + 2 * NEXP * T_TOK) * sizeof(int), stream);
    hipMemsetAsync(out, 0, (size_t)T_TOK * ODIM * sizeof(float), stream);

    cvt_bf16_vec<<<(T_TOK * DDIM / 4) / 256, 256, 0, stream>>>(x, Xb, T_TOK * DDIM / 4);
    transpose_cvt<<<dim3(ODIM / 64, DDIM / 64, NEXP), 256, 0, stream>>>(W1, W1T, DDIM, ODIM);
    transpose_cvt<<<dim3(ODIM / 64, ODIM / 64, NEXP), 256, 0, stream>>>(W2, W2T, ODIM, ODIM);
    router_kernel<<<T_TOK / 4, 256, 0, stream>>>(x, Wg, bg, counts, perm, wlist);

    for (int e = 0; e < NEXP; e++) {
        moe_gemm<0, DDIM><<<dim3(ODIM / 128, T_TOK / 128), 256, 0, stream>>>(
            Xb, W1T + (size_t)e * ODIM * DDIM, b1 + e * ODIM,
            H, nullptr, perm + e * T_TOK, nullptr, counts + e);
        moe_gemm<1, ODIM><<<dim3(ODIM / 128, T_TOK / 128), 256, 0, stream>>>(
            H, W2T + (size_t)e * ODIM * ODIM, b2 + e * ODIM,
            nullptr, out, perm + e * T_TOK, wlist + e * T_TOK, counts + e);
    }
    ln_kernel<<<T_TOK, 256, 0, stream>>>(out, lnw, lnb, gsc);
}